// Round 1
// baseline (119.660 us; speedup 1.0000x reference)
//
#include <hip/hip_runtime.h>
#include <hip/hip_bf16.h>
#include <stdint.h>

// KANExpert: out[b,j] = sum_{i,g} basis(x[b,i])[g] * coeff[i,j,g] * scaling[i,j]
// == GEMM M=4096(batch) N=512(out) K=4096(=512 in_dim * 8 basis), bf16 MFMA.
//
// R0 theory: compute-bound (AI ~680 FLOP/B). Precompute A(basis) and W^T in ws
// (36 MB), then 64x64x64-tile MFMA GEMM with global_load_lds + XOR-swizzled LDS.
// Fallback (ws too small): compute basis/W on the fly into LDS.

#define BATCH   4096
#define IN_DIM  512
#define OUT_DIM 512
#define KDIM    (IN_DIM * 8)   // 4096

typedef short short8 __attribute__((ext_vector_type(8)));
typedef float f32x4  __attribute__((ext_vector_type(4)));

// float -> bf16 bits, round-to-nearest-even
__device__ __forceinline__ unsigned short f2bf(float f) {
  union { float f; unsigned int u; } v; v.f = f;
  unsigned int r = v.u + 0x7FFFu + ((v.u >> 16) & 1u);
  return (unsigned short)(r >> 16);
}

// Uniform cubic B-spline window: x in [-1,1), h=0.4, knots t_n = -1 + 0.4 n.
// Interval m = floor((x+1)/h) in [0,4]; nonzero basis indices n = m-3..m.
__device__ __forceinline__ void bspline_win(float xv, float* w, int* mm) {
  float t = (xv + 1.0f) * 2.5f;
  int m = (int)t;                      // t >= 0 so trunc == floor
  m = m < 0 ? 0 : (m > 4 ? 4 : m);
  float u  = t - (float)m;
  float u2 = u * u, u3 = u2 * u, om = 1.0f - u;
  w[0] = om * om * om * (1.0f / 6.0f);                          // n = m-3
  w[1] = (3.0f * u3 - 6.0f * u2 + 4.0f) * (1.0f / 6.0f);        // n = m-2
  w[2] = (-3.0f * u3 + 3.0f * u2 + 3.0f * u + 1.0f) * (1.0f / 6.0f); // n = m-1
  w[3] = u3 * (1.0f / 6.0f);                                    // n = m
  *mm = m;
}

// All 8 basis values of one (b,i) packed as bf16 (indices outside window = 0).
__device__ __forceinline__ short8 basis_pack8(float xv) {
  float w[4]; int m;
  bspline_win(xv, w, &m);
  short8 h = {};
#pragma unroll
  for (int g = 0; g < 8; ++g) {
    int d = g - m + 3;
    float v = (d == 0) ? w[0] : (d == 1) ? w[1] : (d == 2) ? w[2] : (d == 3) ? w[3] : 0.0f;
    h[g] = (short)f2bf(v);
  }
  return h;
}

// 16B/lane async global->LDS. LDS dest is wave-uniform base + lane*16.
__device__ __forceinline__ void async_load16(const void* g, void* l) {
  __builtin_amdgcn_global_load_lds(
      (__attribute__((address_space(1))) void*)(uintptr_t)g,
      (__attribute__((address_space(3))) void*)(unsigned int)(uintptr_t)l,
      16, 0, 0);
}

// ---- precompute kernels ------------------------------------------------

// Ag[b*4096 + i*8 + g] = bf16 basis. idx = b*512 + i; store = 16B coalesced.
__global__ void kan_basis(const float* __restrict__ x, unsigned short* __restrict__ Ag) {
  int idx = blockIdx.x * 256 + threadIdx.x;        // 0 .. 2M-1
  short8 h = basis_pack8(x[idx]);
  *reinterpret_cast<short8*>(Ag + (size_t)idx * 8) = h;
}

// Wt[j*4096 + i*8 + g] = bf16(coeff[i,j,g] * scaling[i,j]). Reads coalesced.
__global__ void kan_pack(const float* __restrict__ coeff, const float* __restrict__ scaling,
                         unsigned short* __restrict__ Wt) {
  int idx = blockIdx.x * 256 + threadIdx.x;        // i*512 + j
  int i = idx >> 9, j = idx & 511;
  float s = scaling[idx];
  const float4* cp = reinterpret_cast<const float4*>(coeff) + (size_t)idx * 2;
  float4 c0 = cp[0], c1 = cp[1];
  short8 h;
  h[0] = (short)f2bf(c0.x * s); h[1] = (short)f2bf(c0.y * s);
  h[2] = (short)f2bf(c0.z * s); h[3] = (short)f2bf(c0.w * s);
  h[4] = (short)f2bf(c1.x * s); h[5] = (short)f2bf(c1.y * s);
  h[6] = (short)f2bf(c1.z * s); h[7] = (short)f2bf(c1.w * s);
  *reinterpret_cast<short8*>(Wt + (size_t)j * KDIM + i * 8) = h;
}

// ---- GEMM --------------------------------------------------------------
// BM=BN=BK=64, 256 thr = 4 waves (2x2), wave tile 32x32 (2x2 of 16x16x32).
// LDS tiles stored row-major, 8 chunks of 16B per row, chunk XOR-swizzled by
// (row&7) -- swizzle applied to the GLOBAL gather address so the LDS write
// stays contiguous in lane order (global_load_lds constraint). ds_read_b128
// then hits all 8 bank groups across 16 lanes (2-way only = free).
template <bool USE_WS>
__global__ __launch_bounds__(256, 2)
void kan_gemm(const float* __restrict__ x, const float* __restrict__ coeff,
              const float* __restrict__ scaling,
              const unsigned short* __restrict__ Ag,
              const unsigned short* __restrict__ Wt,
              float* __restrict__ out) {
  __shared__ unsigned short As[64 * 64];
  __shared__ unsigned short Bs[64 * 64];

  const int tid  = threadIdx.x;
  const int lane = tid & 63;
  const int wid  = tid >> 6;
  const int wm = wid >> 1, wn = wid & 1;
  const int ln = lane & 15, quad = lane >> 4;
  const int row0 = blockIdx.y * 64;   // batch tile
  const int col0 = blockIdx.x * 64;   // out-col tile

  f32x4 acc[2][2] = {};

  const int lr = lane >> 3;           // row within an 8-row staging inst
  const int cg = (lane & 7) ^ lr;     // swizzled 16B-chunk to fetch

  for (int kt = 0; kt < KDIM / 64; ++kt) {
    const int k0 = kt * 64;
    if constexpr (USE_WS) {
#pragma unroll
      for (int t = 0; t < 2; ++t) {
        const int rbase = wid * 16 + t * 8;                       // wave-uniform
        const unsigned short* ga = Ag + (size_t)(row0 + rbase + lr) * KDIM + k0 + cg * 8;
        async_load16(ga, &As[rbase * 64]);
        const unsigned short* gb = Wt + (size_t)(col0 + rbase + lr) * KDIM + k0 + cg * 8;
        async_load16(gb, &Bs[rbase * 64]);
      }
    } else {
      // on-the-fly staging: 512 (row,i) pairs, 2 per thread, for each tile
#pragma unroll
      for (int pp = 0; pp < 2; ++pp) {
        const int p  = tid + pp * 256;
        const int rn = p & 63;          // A-row (batch) / B-row (out col)
        const int il = p >> 6;          // 0..7: i within this K-tile
        const int sw = ((il ^ (rn & 7)) * 8);
        // A: basis from x
        short8 ha = basis_pack8(x[(size_t)(row0 + rn) * IN_DIM + kt * 8 + il]);
        *reinterpret_cast<short8*>(&As[rn * 64 + sw]) = ha;
        // B: gather coeff*scaling
        const float* cbase = coeff + (size_t)(kt * 8 + il) * 4096 + (size_t)(col0 + rn) * 8;
        float4 c0 = reinterpret_cast<const float4*>(cbase)[0];
        float4 c1 = reinterpret_cast<const float4*>(cbase)[1];
        float s = scaling[(size_t)(kt * 8 + il) * OUT_DIM + col0 + rn];
        short8 hb;
        hb[0] = (short)f2bf(c0.x * s); hb[1] = (short)f2bf(c0.y * s);
        hb[2] = (short)f2bf(c0.z * s); hb[3] = (short)f2bf(c0.w * s);
        hb[4] = (short)f2bf(c1.x * s); hb[5] = (short)f2bf(c1.y * s);
        hb[6] = (short)f2bf(c1.z * s); hb[7] = (short)f2bf(c1.w * s);
        *reinterpret_cast<short8*>(&Bs[rn * 64 + sw]) = hb;
      }
    }
    __syncthreads();   // drains vmcnt (async loads) / lgkm (ds writes)

#pragma unroll
    for (int kk = 0; kk < 2; ++kk) {
      short8 af[2], bfr[2];
#pragma unroll
      for (int mt = 0; mt < 2; ++mt) {
        const int r  = wm * 32 + mt * 16 + ln;
        const int pc = (kk * 4 + quad) ^ (r & 7);
        af[mt] = *reinterpret_cast<const short8*>(&As[r * 64 + pc * 8]);
      }
#pragma unroll
      for (int nt = 0; nt < 2; ++nt) {
        const int c  = wn * 32 + nt * 16 + ln;
        const int pc = (kk * 4 + quad) ^ (c & 7);
        bfr[nt] = *reinterpret_cast<const short8*>(&Bs[c * 64 + pc * 8]);
      }
#pragma unroll
      for (int mt = 0; mt < 2; ++mt)
#pragma unroll
        for (int nt = 0; nt < 2; ++nt)
          acc[mt][nt] = __builtin_amdgcn_mfma_f32_16x16x32_bf16(af[mt], bfr[nt], acc[mt][nt], 0, 0, 0);
    }
    __syncthreads();
  }

  // C/D layout: col = lane&15, row = quad*4 + reg  (m89/m91-verified)
#pragma unroll
  for (int mt = 0; mt < 2; ++mt)
#pragma unroll
    for (int nt = 0; nt < 2; ++nt) {
      const int col = col0 + wn * 32 + nt * 16 + ln;
#pragma unroll
      for (int r = 0; r < 4; ++r) {
        const int row = row0 + wm * 32 + mt * 16 + quad * 4 + r;
        out[(size_t)row * OUT_DIM + col] = acc[mt][nt][r];
      }
    }
}

// ---- launch ------------------------------------------------------------
extern "C" void kernel_launch(void* const* d_in, const int* in_sizes, int n_in,
                              void* d_out, int out_size, void* d_ws, size_t ws_size,
                              hipStream_t stream) {
  const float* x       = (const float*)d_in[0];
  const float* coeff   = (const float*)d_in[1];
  const float* scaling = (const float*)d_in[2];
  float* out = (float*)d_out;

  const size_t needA = (size_t)BATCH * KDIM * 2;     // 32 MB bf16 basis
  const size_t needW = (size_t)OUT_DIM * KDIM * 2;   // 4 MB bf16 W^T

  if (ws_size >= needA + needW) {
    unsigned short* Ag = (unsigned short*)d_ws;
    unsigned short* Wt = (unsigned short*)((char*)d_ws + needA);
    kan_basis<<<(BATCH * IN_DIM) / 256, 256, 0, stream>>>(x, Ag);
    kan_pack<<<(IN_DIM * OUT_DIM) / 256, 256, 0, stream>>>(coeff, scaling, Wt);
    kan_gemm<true><<<dim3(OUT_DIM / 64, BATCH / 64), 256, 0, stream>>>(
        x, coeff, scaling, Ag, Wt, out);
  } else {
    kan_gemm<false><<<dim3(OUT_DIM / 64, BATCH / 64), 256, 0, stream>>>(
        x, coeff, scaling, nullptr, nullptr, out);
  }
}